// Round 2
// baseline (610.280 us; speedup 1.0000x reference)
//
#include <hip/hip_runtime.h>
#include <cstddef>
#include <cstdint>

// ---------------------------------------------------------------------------
// Problem constants (ImplicitHead2D_Seq_MS_Deform)
// ---------------------------------------------------------------------------
#define B_    8
#define NQ_   900
#define C_    256
#define M_    8
#define P_    4
#define L_    4
#define D_    32
#define S_    19560
#define NC_   10
#define FFN_  1024
#define RQ_   (B_ * NQ_)   // 7200 query rows
#define RV_   (B_ * S_)    // 156480 value rows

// SHAPES = ((92,160),(46,80),(23,40),(12,20))
// sizes: 14720, 3680, 920, 240 ; starts: 0, 14720, 18400, 19320

typedef __attribute__((ext_vector_type(8))) short bf8_t;   // 8 x bf16 (4 VGPRs)
typedef __attribute__((ext_vector_type(4))) float f4_t;    // 4 x f32

__device__ __forceinline__ unsigned short f2bf(float x) {
    union { float f; unsigned u; } v; v.f = x;
    unsigned r = v.u + 0x7FFF + ((v.u >> 16) & 1);   // round-nearest-even
    return (unsigned short)(r >> 16);
}

// ---------------------------------------------------------------------------
// Weight prep: convert fp32 W[K][N] -> bf16 W^T[N][K].  64x64 tiles via LDS.
// mat ids: 0=w_value(256x256) 1=w_off|w_attn(256x384 fused) 2=w_out(256x256)
//          3=w_ffn1(256x1024) 4=w_ffn2(1024x256)
// ---------------------------------------------------------------------------
__global__ __launch_bounds__(256) void prep_weights(
    const float* __restrict__ w_value, const float* __restrict__ w_off,
    const float* __restrict__ w_attn,  const float* __restrict__ w_out,
    const float* __restrict__ w_ffn1,  const float* __restrict__ w_ffn2,
    short* __restrict__ WvT, short* __restrict__ WoaT, short* __restrict__ WoutT,
    short* __restrict__ Wf1T, short* __restrict__ Wf2T)
{
    const int mat = blockIdx.z;
    int K, N; const float* src; short* dst;
    switch (mat) {
        case 0: K = 256;  N = 256;  src = w_value; dst = WvT;  break;
        case 1: K = 256;  N = 384;  src = nullptr; dst = WoaT; break;
        case 2: K = 256;  N = 256;  src = w_out;   dst = WoutT; break;
        case 3: K = 256;  N = 1024; src = w_ffn1;  dst = Wf1T; break;
        default:K = 1024; N = 256;  src = w_ffn2;  dst = Wf2T; break;
    }
    const int ntn = N >> 6;
    const int kt = blockIdx.x / ntn, nt = blockIdx.x % ntn;
    if (kt >= (K >> 6)) return;

    __shared__ float t[64][65];
    const int tx = threadIdx.x & 63;
    const int ty = threadIdx.x >> 6;
#pragma unroll
    for (int i = 0; i < 64; i += 4) {
        const int k = kt * 64 + i + ty;
        const int n = nt * 64 + tx;
        float v;
        if (mat == 1) v = (n < 256) ? w_off[(size_t)k * 256 + n]
                                    : w_attn[(size_t)k * 128 + (n - 256)];
        else          v = src[(size_t)k * N + n];
        t[i + ty][tx] = v;
    }
    __syncthreads();
#pragma unroll
    for (int i = 0; i < 64; i += 4) {
        const int n = nt * 64 + i + ty;
        const int k = kt * 64 + tx;
        dst[(size_t)n * K + k] = (short)f2bf(t[tx][i + ty]);
    }
}

__global__ __launch_bounds__(384) void prep_bias(
    const float* __restrict__ b_off, const float* __restrict__ b_attn,
    float* __restrict__ bias_cat)
{
    const int t = threadIdx.x;
    bias_cat[t] = (t < 256) ? b_off[t] : b_attn[t - 256];
}

// ---------------------------------------------------------------------------
// bf16 MFMA GEMM:  out[R,N] = A[R,K](fp32) @ W(bf16, stored as W^T[N][K]) + bias
//  MODE 0: plain   MODE 1: value-permute -> v[B,M,S,D]   MODE 2: relu
//  MODE 3: residual (+res[r*N+n])
// 128x128 tile, 4 waves (2x2), each wave 64x64 via 4x4 mfma_16x16x32 frags.
// BK=64. LDS As/Bs [128][64] bf16, XOR-swizzled on 16B units: unit u at row r
// holds k-chunk (u ^ (r&7))*8..+7  -> conflict-free-ish ds_read_b128.
// A staged with fused fp32->bf16 convert; B staged as int4 copies.
// Requires: N % 128 == 0, K % 64 == 0. Rows guarded vs R.
// ---------------------------------------------------------------------------
template <int MODE>
__global__ __launch_bounds__(256) void gemm_mfma(
    const float* __restrict__ A, const short* __restrict__ WT,
    const float* __restrict__ bias, const float* __restrict__ res,
    float* __restrict__ out, int R, int N, int K)
{
    __shared__ __align__(16) short As[128 * 64];
    __shared__ __align__(16) short Bs[128 * 64];

    const int tid  = threadIdx.x;
    const int lane = tid & 63;
    const int wave = tid >> 6;
    const int wr   = wave >> 1;       // 0..1 wave row
    const int wc   = wave & 1;        // 0..1 wave col
    const int g    = lane >> 4;       // k-group 0..3
    const int fr   = lane & 15;       // fragment row/col

    const int row0 = blockIdx.x * 128;
    const int col0 = blockIdx.y * 128;

    f4_t acc[4][4] = {};

    for (int k0 = 0; k0 < K; k0 += 64) {
        // ---- stage A (fp32 -> bf16, swizzled write) ----
#pragma unroll
        for (int it = 0; it < 4; ++it) {
            const int unit = it * 256 + tid;      // 0..1023
            const int r    = unit >> 3;           // local row 0..127
            const int ku   = unit & 7;            // k-chunk 0..7
            float va[8] = {0.f, 0.f, 0.f, 0.f, 0.f, 0.f, 0.f, 0.f};
            const int grow = row0 + r;
            if (grow < R) {
                const float4 p0 = *(const float4*)(A + (size_t)grow * K + k0 + ku * 8);
                const float4 p1 = *(const float4*)(A + (size_t)grow * K + k0 + ku * 8 + 4);
                va[0] = p0.x; va[1] = p0.y; va[2] = p0.z; va[3] = p0.w;
                va[4] = p1.x; va[5] = p1.y; va[6] = p1.z; va[7] = p1.w;
            }
            bf8_t pk;
#pragma unroll
            for (int j = 0; j < 8; ++j) pk[j] = (short)f2bf(va[j]);
            const int u = ku ^ (r & 7);
            *(bf8_t*)&As[r * 64 + u * 8] = pk;
        }
        // ---- stage B (bf16 copy, swizzled write) ----
#pragma unroll
        for (int it = 0; it < 4; ++it) {
            const int unit = it * 256 + tid;
            const int n    = unit >> 3;           // local col-row 0..127
            const int ku   = unit & 7;
            const int u    = ku ^ (n & 7);
            const int4 w = *(const int4*)(WT + (size_t)(col0 + n) * K + k0 + ku * 8);
            *(int4*)&Bs[n * 64 + u * 8] = w;
        }
        __syncthreads();

        // ---- MFMA: 2 k-chunks of 32 ----
#pragma unroll
        for (int c = 0; c < 2; ++c) {
            bf8_t a[4], b[4];
#pragma unroll
            for (int i = 0; i < 4; ++i) {
                const int ar = wr * 64 + i * 16 + fr;
                const int au = (c * 4 + g) ^ (ar & 7);
                a[i] = *(const bf8_t*)&As[ar * 64 + au * 8];
                const int br = wc * 64 + i * 16 + fr;
                const int bu = (c * 4 + g) ^ (br & 7);
                b[i] = *(const bf8_t*)&Bs[br * 64 + bu * 8];
            }
#pragma unroll
            for (int i = 0; i < 4; ++i)
#pragma unroll
                for (int j = 0; j < 4; ++j)
                    acc[i][j] = __builtin_amdgcn_mfma_f32_16x16x32_bf16(
                        a[i], b[j], acc[i][j], 0, 0, 0);
        }
        __syncthreads();
    }

    // ---- epilogue ----
    // D layout (m89-verified): col = lane&15, row = (lane>>4)*4 + reg
#pragma unroll
    for (int j = 0; j < 4; ++j) {
        const int col = col0 + wc * 64 + j * 16 + fr;
        const float bcol = bias[col];
#pragma unroll
        for (int i = 0; i < 4; ++i) {
#pragma unroll
            for (int r = 0; r < 4; ++r) {
                const int row = row0 + wr * 64 + i * 16 + g * 4 + r;
                if (row >= R) continue;
                float vv = acc[i][j][r] + bcol;
                if (MODE == 1) {
                    const int b = row / S_;
                    const int s = row - b * S_;
                    const int m = col >> 5;
                    const int d = col & 31;
                    out[(((size_t)(b * M_ + m)) * S_ + s) * D_ + d] = vv;
                } else if (MODE == 2) {
                    out[(size_t)row * N + col] = fmaxf(vv, 0.f);
                } else if (MODE == 3) {
                    out[(size_t)row * N + col] = vv + res[(size_t)row * N + col];
                } else {
                    out[(size_t)row * N + col] = vv;
                }
            }
        }
    }
}

// ---------------------------------------------------------------------------
// Softmax over L*P=16 per head + bake sampling locations to pixel coords.
// oa row layout: [0..255] = off (m*32+l*8+p*2+c), [256..383] = attn logits
// (m*16+l*4+p).  loc: pixel coords x_px = ref_x*Wl + off_x - 0.5.
// ---------------------------------------------------------------------------
__global__ __launch_bounds__(128) void softmax_loc_kernel(
    const float* __restrict__ oa, const float* __restrict__ ref,
    float* __restrict__ loc, float* __restrict__ attn)
{
    const int row = blockIdx.x;
    const int t   = threadIdx.x;       // 0..127 (m = t>>4)
    const float Wtab[L_] = {160.f, 80.f, 40.f, 20.f};
    const float Htab[L_] = {92.f, 46.f, 23.f, 12.f};

    float vlog = oa[(size_t)row * 384 + 256 + t];
    float mx = vlog;
#pragma unroll
    for (int o = 8; o >= 1; o >>= 1) mx = fmaxf(mx, __shfl_xor(mx, o, 64));
    const float e = __expf(vlog - mx);
    float sm = e;
#pragma unroll
    for (int o = 8; o >= 1; o >>= 1) sm += __shfl_xor(sm, o, 64);
    attn[(size_t)row * 128 + t] = e / sm;

    const int m = t >> 4, l = (t >> 2) & 3, p = t & 3;
    const float rx = ref[(size_t)row * 2 + 0];
    const float ry = ref[(size_t)row * 2 + 1];
    const int oi = m * 32 + l * 8 + p * 2;
    loc[(size_t)row * 256 + oi + 0] = rx * Wtab[l] + oa[(size_t)row * 384 + oi + 0] - 0.5f;
    loc[(size_t)row * 256 + oi + 1] = ry * Htab[l] + oa[(size_t)row * 384 + oi + 1] - 0.5f;
}

// ---------------------------------------------------------------------------
// Deformable sampling. grid = 7200, block 256: thread = (m=t>>5, d=t&31).
// v layout [B, M, S, D]; output feat[row][m*32+d].
// ---------------------------------------------------------------------------
__global__ __launch_bounds__(256) void sample_kernel(
    const float* __restrict__ v, const float* __restrict__ loc,
    const float* __restrict__ attn, float* __restrict__ outf)
{
    const int row = blockIdx.x;
    const int b   = row / NQ_;
    const int t   = threadIdx.x;
    const int m   = t >> 5;
    const int d   = t & 31;

    __shared__ float sloc[256];
    __shared__ float satt[128];
    sloc[t] = loc[(size_t)row * 256 + t];
    if (t < 128) satt[t] = attn[(size_t)row * 128 + t];
    __syncthreads();

    const int Wtab[L_] = {160, 80, 40, 20};
    const int Htab[L_] = {92, 46, 23, 12};
    const int Stab[L_] = {0, 14720, 18400, 19320};

    const float* vb = v + ((size_t)(b * M_ + m)) * S_ * D_ + d;
    float acc = 0.f;

#pragma unroll
    for (int l = 0; l < L_; ++l) {
        const int Wl = Wtab[l], Hl = Htab[l], st = Stab[l];
#pragma unroll
        for (int p = 0; p < P_; ++p) {
            const float x = sloc[m * 32 + l * 8 + p * 2 + 0];
            const float y = sloc[m * 32 + l * 8 + p * 2 + 1];
            const float a = satt[m * 16 + l * 4 + p];
            const float xf = floorf(x), yf = floorf(y);
            const int x0 = (int)xf, y0 = (int)yf;
            const float lx = x - xf, ly = y - yf;
            const float w00 = (1.f - lx) * (1.f - ly);
            const float w01 = lx * (1.f - ly);
            const float w10 = (1.f - lx) * ly;
            const float w11 = lx * ly;
            const bool xv0 = (x0 >= 0) && (x0 < Wl);
            const bool xv1 = (x0 + 1 >= 0) && (x0 + 1 < Wl);
            const bool yv0 = (y0 >= 0) && (y0 < Hl);
            const bool yv1 = (y0 + 1 >= 0) && (y0 + 1 < Hl);
            float s00 = 0.f, s01 = 0.f, s10 = 0.f, s11 = 0.f;
            if (xv0 && yv0) s00 = vb[(size_t)(st + y0 * Wl + x0) * D_];
            if (xv1 && yv0) s01 = vb[(size_t)(st + y0 * Wl + x0 + 1) * D_];
            if (xv0 && yv1) s10 = vb[(size_t)(st + (y0 + 1) * Wl + x0) * D_];
            if (xv1 && yv1) s11 = vb[(size_t)(st + (y0 + 1) * Wl + x0 + 1) * D_];
            acc += a * (w00 * s00 + w01 * s01 + w10 * s10 + w11 * s11);
        }
    }
    outf[(size_t)row * 256 + m * 32 + d] = acc;
}

// ---------------------------------------------------------------------------
// LayerNorm over C=256. grid = 7200, block = 64 (one wave), float4 per lane.
// ---------------------------------------------------------------------------
__global__ __launch_bounds__(64) void ln_kernel(
    const float* __restrict__ in, const float* __restrict__ w,
    const float* __restrict__ bp, float* __restrict__ out)
{
    const int row  = blockIdx.x;
    const int lane = threadIdx.x;
    const float4 x = ((const float4*)(in + (size_t)row * C_))[lane];
    float s = x.x + x.y + x.z + x.w;
#pragma unroll
    for (int o = 32; o >= 1; o >>= 1) s += __shfl_xor(s, o, 64);
    const float mean = s * (1.f / C_);
    const float d0 = x.x - mean, d1 = x.y - mean, d2 = x.z - mean, d3 = x.w - mean;
    float ss = d0 * d0 + d1 * d1 + d2 * d2 + d3 * d3;
#pragma unroll
    for (int o = 32; o >= 1; o >>= 1) ss += __shfl_xor(ss, o, 64);
    const float r = rsqrtf(ss * (1.f / C_) + 1e-6f);
    const float4 wv = ((const float4*)w)[lane];
    const float4 bv = ((const float4*)bp)[lane];
    float4 o4;
    o4.x = d0 * r * wv.x + bv.x;
    o4.y = d1 * r * wv.y + bv.y;
    o4.z = d2 * r * wv.z + bv.z;
    o4.w = d3 * r * wv.w + bv.w;
    ((float4*)(out + (size_t)row * C_))[lane] = o4;
}

// ---------------------------------------------------------------------------
// Classifier head: out[row,0..9] = x[row,:] @ w_cls + b_cls. grid=7200, block=64.
// ---------------------------------------------------------------------------
__global__ __launch_bounds__(64) void cls_kernel(
    const float* __restrict__ x, const float* __restrict__ w,
    const float* __restrict__ bias, float* __restrict__ out)
{
    const int row  = blockIdx.x;
    const int lane = threadIdx.x;
    float acc[NC_] = {};
#pragma unroll
    for (int j = 0; j < 4; ++j) {
        const int k = lane + j * 64;
        const float xk = x[(size_t)row * C_ + k];
        const float* wr = w + (size_t)k * NC_;
#pragma unroll
        for (int n = 0; n < NC_; ++n) acc[n] += xk * wr[n];
    }
#pragma unroll
    for (int n = 0; n < NC_; ++n) {
        float s = acc[n];
#pragma unroll
        for (int o = 32; o >= 1; o >>= 1) s += __shfl_xor(s, o, 64);
        if (lane == n) out[(size_t)row * NC_ + n] = s + bias[n];
    }
}

// ---------------------------------------------------------------------------
extern "C" void kernel_launch(void* const* d_in, const int* in_sizes, int n_in,
                              void* d_out, int out_size, void* d_ws, size_t ws_size,
                              hipStream_t stream)
{
    const float* query   = (const float*)d_in[0];
    const float* value   = (const float*)d_in[1];
    const float* refp    = (const float*)d_in[2];
    const float* w_value = (const float*)d_in[3];
    const float* b_value = (const float*)d_in[4];
    const float* w_off   = (const float*)d_in[5];
    const float* b_off   = (const float*)d_in[6];
    const float* w_attn  = (const float*)d_in[7];
    const float* b_attn  = (const float*)d_in[8];
    const float* w_out   = (const float*)d_in[9];
    const float* b_out   = (const float*)d_in[10];
    const float* ln1w    = (const float*)d_in[11];
    const float* ln1b    = (const float*)d_in[12];
    const float* w_ffn1  = (const float*)d_in[13];
    const float* b_ffn1  = (const float*)d_in[14];
    const float* w_ffn2  = (const float*)d_in[15];
    const float* b_ffn2  = (const float*)d_in[16];
    const float* ln2w    = (const float*)d_in[17];
    const float* ln2b    = (const float*)d_in[18];
    const float* w_cls   = (const float*)d_in[19];
    const float* b_cls   = (const float*)d_in[20];

    // ---- workspace layout (bf16 weights first, 16B-aligned) ----
    short* WvT   = (short*)d_ws;            //  65536
    short* WoaT  = WvT  + 65536;            //  98304 (384x256)
    short* WoutT = WoaT + 98304;            //  65536
    short* Wf1T  = WoutT + 65536;           // 262144 (1024x256)
    short* Wf2T  = Wf1T + 262144;           // 262144 (256x1024)
    float* bias_cat = (float*)(Wf2T + 262144);          // 384
    float* v    = bias_cat + 384;                       // [B,M,S,D] 40,058,880
    float* oa   = v    + (size_t)RV_ * C_;              // [RQ,384]   2,764,800
    float* loc  = oa   + (size_t)RQ_ * 384;             // [RQ,256]
    float* attn = loc  + (size_t)RQ_ * 256;             // [RQ,128]
    float* feat = attn + (size_t)RQ_ * 128;             // [RQ,256]
    float* tmp  = feat + (size_t)RQ_ * 256;             // [RQ,256]
    float* h    = tmp  + (size_t)RQ_ * 256;             // [RQ,1024]
    float* x2   = h    + (size_t)RQ_ * FFN_;            // [RQ,256]

    // 0) weight prep (bf16 + transpose), bias concat
    prep_weights<<<dim3(64, 1, 5), 256, 0, stream>>>(
        w_value, w_off, w_attn, w_out, w_ffn1, w_ffn2,
        WvT, WoaT, WoutT, Wf1T, Wf2T);
    prep_bias<<<1, 384, 0, stream>>>(b_off, b_attn, bias_cat);

    // 1) v = value @ w_value + b_value  -> [B,M,S,D]
    gemm_mfma<1><<<dim3((RV_ + 127) / 128, 2), 256, 0, stream>>>(
        value, WvT, b_value, nullptr, v, RV_, 256, 256);

    // 2) fused off|attn logits
    gemm_mfma<0><<<dim3((RQ_ + 127) / 128, 3), 256, 0, stream>>>(
        query, WoaT, bias_cat, nullptr, oa, RQ_, 384, 256);

    // 3) softmax + pixel-coord locations
    softmax_loc_kernel<<<RQ_, 128, 0, stream>>>(oa, refp, loc, attn);

    // 4) deformable sampling -> feat [RQ, C]
    sample_kernel<<<RQ_, 256, 0, stream>>>(v, loc, attn, feat);

    // 5) tmp = query + feat @ w_out + b_out
    gemm_mfma<3><<<dim3((RQ_ + 127) / 128, 2), 256, 0, stream>>>(
        feat, WoutT, b_out, query, tmp, RQ_, 256, 256);

    // 6) x1 = LN(tmp) -> feat reused
    ln_kernel<<<RQ_, 64, 0, stream>>>(tmp, ln1w, ln1b, feat);

    // 7) h = relu(x1 @ w_ffn1 + b_ffn1)
    gemm_mfma<2><<<dim3((RQ_ + 127) / 128, 8), 256, 0, stream>>>(
        feat, Wf1T, b_ffn1, nullptr, h, RQ_, 1024, 256);

    // 8) tmp = x1 + h @ w_ffn2 + b_ffn2
    gemm_mfma<3><<<dim3((RQ_ + 127) / 128, 2), 256, 0, stream>>>(
        h, Wf2T, b_ffn2, feat, tmp, RQ_, 256, 1024);

    // 9) x2 = LN(tmp)
    ln_kernel<<<RQ_, 64, 0, stream>>>(tmp, ln2w, ln2b, x2);

    // 10) out = x2 @ w_cls + b_cls
    cls_kernel<<<RQ_, 64, 0, stream>>>(x2, w_cls, b_cls, (float*)d_out);
}